// Round 5
// baseline (380.904 us; speedup 1.0000x reference)
//
#include <hip/hip_runtime.h>

#define W_ 160
#define H_ 96
#define C_ 128
#define B_ 16
#define TX 32
#define TY 16
#define NBX 5
#define NBY 6
#define NTILE (B_ * NBY * NBX)    // 480
#define NWG   ((NTILE * 9) / 4)   // 1080 = 8 * 135

__global__ __launch_bounds__(256, 3) void corr_kernel(
    const float* __restrict__ in1,
    const float* __restrict__ in2,
    float* __restrict__ out)
{
    // XCD-chunked bijective block swizzle (1080 = 8*135): consecutive logical
    // waves (which share a pixel tile across dy) land on the same XCD's L2.
    const int L    = ((int)blockIdx.x & 7) * (NWG / 8) + ((int)blockIdx.x >> 3);
    const int tid  = threadIdx.x;
    const int lane = tid & 63;
    const int wid  = __builtin_amdgcn_readfirstlane(L * 4 + (tid >> 6)); // wave-uniform -> SGPR
    const int tile = wid / 9;
    const int dyi  = wid - tile * 9;          // 0..8  (dy = dyi-4)
    const int dy   = dyi - 4;
    const int b    = tile / (NBY * NBX);
    const int rem  = tile - b * (NBY * NBX);
    const int by   = rem / NBX;
    const int bx   = rem - by * NBX;
    const int x0 = bx * TX, y0 = by * TY;

    const int q  = lane & 3;                  // x-quad (8 px)
    const int r  = lane >> 2;                 // row 0..15
    const int y  = y0 + r;
    const int xb = x0 + 8 * q;

    const int gy2 = y + dy;
    const int ry2 = min(max(gy2, 0), H_ - 1);                 // clamped (fault-safe)
    const float ym = ((unsigned)gy2 < (unsigned)H_) ? 1.f : 0.f;

    const size_t HW = (size_t)H_ * W_;
    const float* i1u = in1 + (size_t)b * C_ * HW;             // SGPR base
    const float* i2u = in2 + (size_t)b * C_ * HW;             // SGPR base

    const int o1 = y * W_ + xb;                               // per-lane voffset, in1
    // in2 window float4 offsets, clamped to stay in-row (clamp only fires when
    // the whole float4 is OOB -> fully masked in the epilogue)
    const int o2a = ry2 * W_ + min(max(xb - 4, 0), W_ - 4);
    const int o2b = ry2 * W_ + min(max(xb + 0, 0), W_ - 4);
    const int o2c = ry2 * W_ + min(max(xb + 4, 0), W_ - 4);
    const int o2d = ry2 * W_ + min(max(xb + 8, 0), W_ - 4);

    float acc[8][9];
#pragma unroll
    for (int p = 0; p < 8; ++p)
#pragma unroll
        for (int d = 0; d < 9; ++d) acc[p][d] = 0.f;

    // 3-slot register pipeline (slot = c % 3), depth-2 prefetch
    float4 A0[3], A1[3], Wv[3][4];

#define LOADC(c, s)                                                            \
    {                                                                          \
        const float* a_ = i1u + (size_t)(c) * HW;                              \
        A0[s] = *(const float4*)(a_ + o1);                                     \
        A1[s] = *(const float4*)(a_ + o1 + 4);                                 \
        const float* w_ = i2u + (size_t)(c) * HW;                              \
        Wv[s][0] = *(const float4*)(w_ + o2a);                                 \
        Wv[s][1] = *(const float4*)(w_ + o2b);                                 \
        Wv[s][2] = *(const float4*)(w_ + o2c);                                 \
        Wv[s][3] = *(const float4*)(w_ + o2d);                                 \
    }

#define FMAC(s)                                                                \
    {                                                                          \
        const float av[8] = {A0[s].x, A0[s].y, A0[s].z, A0[s].w,               \
                             A1[s].x, A1[s].y, A1[s].z, A1[s].w};              \
        const float wf[16] = {Wv[s][0].x, Wv[s][0].y, Wv[s][0].z, Wv[s][0].w,  \
                              Wv[s][1].x, Wv[s][1].y, Wv[s][1].z, Wv[s][1].w,  \
                              Wv[s][2].x, Wv[s][2].y, Wv[s][2].z, Wv[s][2].w,  \
                              Wv[s][3].x, Wv[s][3].y, Wv[s][3].z, Wv[s][3].w}; \
        _Pragma("unroll")                                                      \
        for (int p = 0; p < 8; ++p)                                            \
            _Pragma("unroll")                                                  \
            for (int d = 0; d < 9; ++d)                                        \
                acc[p][d] = fmaf(av[p], wf[p + d], acc[p][d]);                 \
    }

    LOADC(0, 0);
    LOADC(1, 1);
#pragma unroll 1
    for (int c = 0; c < C_ - 2; c += 3) {   // c = 0,3,...,123
        LOADC(c + 2, 2);
        FMAC(0);                            // cc = c
        LOADC(c + 3, 0);
        FMAC(1);                            // cc = c+1
        LOADC(c + 4, 1);
        FMAC(2);                            // cc = c+2
    }
    FMAC(0);                                // cc = 126
    FMAC(1);                                // cc = 127
#undef LOADC
#undef FMAC

    // Epilogue: out[b][dyi*9+d][y][x] = acc * ms[p+d]; OOB (dy,dx) -> exact 0
    float ms[16];
#pragma unroll
    for (int j = 0; j < 16; ++j)
        ms[j] = (((unsigned)(xb - 4 + j)) < (unsigned)W_) ? ym * (1.f / 128.f) : 0.f;

    const size_t ob = (((size_t)(b * 81 + dyi * 9)) * H_ + y) * W_ + xb;
#pragma unroll
    for (int d = 0; d < 9; ++d) {
        float4 v0, v1;
        v0.x = acc[0][d] * ms[0 + d]; v0.y = acc[1][d] * ms[1 + d];
        v0.z = acc[2][d] * ms[2 + d]; v0.w = acc[3][d] * ms[3 + d];
        v1.x = acc[4][d] * ms[4 + d]; v1.y = acc[5][d] * ms[5 + d];
        v1.z = acc[6][d] * ms[6 + d]; v1.w = acc[7][d] * ms[7 + d];
        float* op = out + ob + (size_t)d * HW;
        *(float4*)(op)     = v0;
        *(float4*)(op + 4) = v1;
    }
}

extern "C" void kernel_launch(void* const* d_in, const int* in_sizes, int n_in,
                              void* d_out, int out_size, void* d_ws, size_t ws_size,
                              hipStream_t stream) {
    const float* in1 = (const float*)d_in[0];
    const float* in2 = (const float*)d_in[1];
    float* out = (float*)d_out;
    (void)in_sizes; (void)n_in; (void)out_size; (void)d_ws; (void)ws_size;
    hipLaunchKernelGGL(corr_kernel, dim3(NWG), dim3(256), 0, stream, in1, in2, out);
}

// Round 6
// 189.934 us; speedup vs baseline: 2.0055x; 2.0055x over previous
//
#include <hip/hip_runtime.h>
#include <stdint.h>

typedef __bf16 bf16;
typedef __attribute__((ext_vector_type(4))) __bf16 bf16x4;
typedef __attribute__((ext_vector_type(8))) __bf16 bf16x8;
typedef __attribute__((ext_vector_type(4))) float f32x4;

#define W_ 160
#define H_ 96
#define C_ 128
#define B_ 16
#define HW_ (H_ * W_)            // 15360
#define NYB 12                   // 96/8
#define NXT 10                   // 160/16
#define NBLK (B_ * NYB * NXT)    // 1920 = 8 * 240
#define NTHR 512
#define XL 24                    // staged x' columns (x0-4 .. x0+19)
#define ROWB 16                  // staged rows (y0-4 .. y0+11)
#define RSTRB (XL * 64)          // 1536 B per LDS row ([xl][c-octet swz][c&7])
#define LDSB (ROWB * RSTRB + 2048)  // pad: t=1 frag overreads xl>=24 (values discarded)

__global__ __launch_bounds__(NTHR, 4) void corr_mfma(
    const float* __restrict__ in1,
    const float* __restrict__ in2,
    float* __restrict__ out)
{
    __shared__ __align__(16) char Bsm[LDSB];

    // XCD-chunked bijective swizzle (1920 = 8*240)
    const int L   = ((int)blockIdx.x & 7) * (NBLK / 8) + ((int)blockIdx.x >> 3);
    const int b   = L / (NYB * NXT);
    const int rem = L % (NYB * NXT);
    const int yb  = rem / NXT;
    const int xt  = rem % NXT;
    const int x0  = xt * 16, y0 = yb * 8;

    const int tid  = threadIdx.x;
    const int w    = tid >> 6;           // wave 0..7 -> y = y0 + w
    const int lane = tid & 63;
    const int n    = lane & 15;          // A-frag row m / B-frag col n
    const int g    = lane >> 4;          // k-octet group (k = 8g..8g+7)
    const int y    = y0 + w;

    const float* i1b = in1 + (size_t)b * C_ * HW_;
    const float* i2b = in2 + (size_t)b * C_ * HW_;

    // ---------- A fragments: A[m=x0+n][k=c], all 128 c upfront ----------
    const float* abase = i1b + (size_t)y * W_ + (x0 + n);
    bf16x8 afrag[4];
#pragma unroll
    for (int ck = 0; ck < 4; ++ck)
#pragma unroll
        for (int j = 0; j < 8; ++j) {
            float f = abase[(size_t)(ck * 32 + g * 8 + j) * HW_];
            afrag[ck][j] = (bf16)f;
        }

    // ---------- staging task: 384 threads = 16 rows x 6 xq x 4 c-octets ----------
    const bool sact = (tid < 384);
    const int srow = tid / 24;
    const int srem = tid % 24;
    const int sxq  = srem >> 2;          // 0..5 (4 x' each)
    const int sg   = srem & 3;           // c-octet
    const int gy2  = y0 - 4 + srow;
    const int gx2  = x0 - 4 + 4 * sxq;
    const bool sval = sact && ((unsigned)gy2 < (unsigned)H_) &&
                      (gx2 >= 0) && (gx2 + 3 < W_);
    const int cy = gy2 < 0 ? 0 : (gy2 >= H_ ? H_ - 1 : gy2);
    const int cx = gx2 < 0 ? 0 : (gx2 > W_ - 4 ? W_ - 4 : gx2);
    const float* sbase = i2b + (size_t)cy * W_ + cx;

    int wb[4];                           // LDS write byte addr per xi
#pragma unroll
    for (int xi = 0; xi < 4; ++xi) {
        int xl = 4 * sxq + xi;
        int sw = sg ^ ((xl >> 1) & 3);
        wb[xi] = srow * RSTRB + xl * 64 + sw * 16;
    }

    int rb[2];                           // B-frag read addr (minus row term)
#pragma unroll
    for (int t = 0; t < 2; ++t) {
        int xl = n + 16 * t;
        int sw = g ^ ((xl >> 1) & 3);
        rb[t] = xl * 64 + sw * 16;
    }

    f32x4 acc[9][2];
#pragma unroll
    for (int dyi = 0; dyi < 9; ++dyi)
#pragma unroll
        for (int t = 0; t < 2; ++t)
            acc[dyi][t] = (f32x4){0.f, 0.f, 0.f, 0.f};

    const float SC = 1.0f / 128.0f;      // exact in bf16 scaling (power of 2)
    const float4 z4 = {0.f, 0.f, 0.f, 0.f};

    for (int ck = 0; ck < 4; ++ck) {
        if (ck) __syncthreads();         // prev chunk's LDS reads complete
        // ---- stage chunk ck: in2 f32 -> (x/128) bf16, zeros pad boundaries ----
#pragma unroll
        for (int jh = 0; jh < 2; ++jh) {
            float4 v[4];
#pragma unroll
            for (int j2 = 0; j2 < 4; ++j2) {
                int c = ck * 32 + sg * 8 + jh * 4 + j2;
                v[j2] = sval ? *(const float4*)(sbase + (size_t)c * HW_) : z4;
            }
#pragma unroll
            for (int xi = 0; xi < 4; ++xi) {
                bf16x4 pk;
                pk[0] = (bf16)(((const float*)&v[0])[xi] * SC);
                pk[1] = (bf16)(((const float*)&v[1])[xi] * SC);
                pk[2] = (bf16)(((const float*)&v[2])[xi] * SC);
                pk[3] = (bf16)(((const float*)&v[3])[xi] * SC);
                if (sact) *(bf16x4*)(Bsm + wb[xi] + 8 * jh) = pk;
            }
        }
        __syncthreads();
        // ---- compute: 9 dy x 2 N-tiles, K=32 per MFMA ----
#pragma unroll
        for (int dyi = 0; dyi < 9; ++dyi) {
            const int rowoff = (w + dyi) * RSTRB;
#pragma unroll
            for (int t = 0; t < 2; ++t) {
                bf16x8 bfrag = *(const bf16x8*)(Bsm + rowoff + rb[t]);
                acc[dyi][t] = __builtin_amdgcn_mfma_f32_16x16x32_bf16(
                    afrag[ck], bfrag, acc[dyi][t], 0, 0, 0);
            }
        }
    }

    // ---------- epilogue: extract diagonals; C/D: col=lane&15, row=4*(lane>>4)+r ----------
#pragma unroll
    for (int dyi = 0; dyi < 9; ++dyi) {
        const size_t base = (((size_t)(b * 81 + dyi * 9)) * H_ + y) * W_;
#pragma unroll
        for (int t = 0; t < 2; ++t)
#pragma unroll
            for (int r = 0; r < 4; ++r) {
                int m = g * 4 + r;                 // x = x0 + m
                int d = n + 16 * t - m;            // dx + 4
                if ((unsigned)d <= 8u)
                    out[base + (size_t)d * HW_ + (x0 + m)] = acc[dyi][t][r];
            }
    }
}

extern "C" void kernel_launch(void* const* d_in, const int* in_sizes, int n_in,
                              void* d_out, int out_size, void* d_ws, size_t ws_size,
                              hipStream_t stream) {
    const float* in1 = (const float*)d_in[0];
    const float* in2 = (const float*)d_in[1];
    float* out = (float*)d_out;
    (void)in_sizes; (void)n_in; (void)out_size; (void)d_ws; (void)ws_size;
    hipLaunchKernelGGL(corr_mfma, dim3(NBLK), dim3(NTHR), 0, stream, in1, in2, out);
}

// Round 7
// 157.598 us; speedup vs baseline: 2.4169x; 1.2052x over previous
//
#include <hip/hip_runtime.h>
#include <stdint.h>

typedef __bf16 bf16;
typedef __attribute__((ext_vector_type(8))) __bf16 bf16x8;
typedef __attribute__((ext_vector_type(4))) float f32x4;

#define W_ 160
#define H_ 96
#define C_ 128
#define B_ 16
#define HW_ (H_ * W_)            // 15360
#define NYB 12                   // 96/8
#define NXT 10                   // 160/16
#define NBLK (B_ * NYB * NXT)    // 1920 = 8 * 240
#define NTHR 512
#define XL 24                    // staged x' columns (x0-4 .. x0+19)
#define ROWB 16                  // staged rows (y0-4 .. y0+11)
#define RSTRB (XL * 64)          // 1536 B per LDS row: [xl][c-octet swz][c&7]
#define BUFB (ROWB * RSTRB + 2048)   // 26624 B (pad: t=1 frag overread, discarded)
#define WSSTR 1312               // floats; per-wave epilogue transpose region

__global__ __launch_bounds__(NTHR, 3) void corr_mfma(
    const float* __restrict__ in1,
    const float* __restrict__ in2,
    float* __restrict__ out)
{
    __shared__ __align__(16) char Bsm[2 * BUFB];   // 53248 B (dbuf; reused by epilogue)

    // XCD-chunked bijective swizzle (1920 = 8*240)
    const int L   = ((int)blockIdx.x & 7) * (NBLK / 8) + ((int)blockIdx.x >> 3);
    const int b   = L / (NYB * NXT);
    const int rem = L % (NYB * NXT);
    const int yb  = rem / NXT;
    const int xt  = rem % NXT;
    const int x0  = xt * 16, y0 = yb * 8;

    const int tid  = threadIdx.x;
    const int w    = tid >> 6;           // wave 0..7 -> y = y0 + w
    const int lane = tid & 63;
    const int n    = lane & 15;          // frag row m (A) / col (B)
    const int g    = lane >> 4;          // k-octet group
    const int y    = y0 + w;

    const float* i1b = in1 + (size_t)b * C_ * HW_;
    const float* i2b = in2 + (size_t)b * C_ * HW_;

    // ---------- A loads (issued first; converted later) ----------
    const float* abase = i1b + (size_t)y * W_ + (x0 + n);
    float a_raw[32];
#pragma unroll
    for (int ck = 0; ck < 4; ++ck)
#pragma unroll
        for (int j = 0; j < 8; ++j)
            a_raw[ck * 8 + j] = abase[(size_t)(ck * 32 + g * 8 + j) * HW_];

    // ---------- staging mapping: 384 threads = 16 rows x 6 xq x 4 c-octets ----------
    const bool sact = (tid < 384);
    const int srow = tid / 24;
    const int srem = tid % 24;
    const int sxq  = srem >> 2;          // 0..5 (4 x' each)
    const int sg   = srem & 3;           // c-octet
    const int gy2  = y0 - 4 + srow;
    const int gx2  = x0 - 4 + 4 * sxq;
    const bool sval = sact && ((unsigned)gy2 < (unsigned)H_) &&
                      (gx2 >= 0) && (gx2 + 3 < W_);
    const int cy = min(max(gy2, 0), H_ - 1);
    const int cx = min(max(gx2, 0), W_ - 4);
    const float* sbase = i2b + (size_t)cy * W_ + cx;

    int wb[4];                           // LDS write byte addr per xi
#pragma unroll
    for (int xi = 0; xi < 4; ++xi) {
        int xl = 4 * sxq + xi;
        int sw = sg ^ ((xl >> 1) & 3);
        wb[xi] = srow * RSTRB + xl * 64 + sw * 16;
    }
    int rb[2];                           // B-frag read addr (minus row term)
#pragma unroll
    for (int t = 0; t < 2; ++t) {
        int xl = n + 16 * t;
        int sw = g ^ ((xl >> 1) & 3);
        rb[t] = xl * 64 + sw * 16;
    }

    const float SC = 1.0f / 128.0f;      // exact power-of-2 fold of the 1/(K*K*C) norm
    const float4 z4 = {0.f, 0.f, 0.f, 0.f};
    float4 sv[8];                        // T14: in-flight staging regs

#define SLOAD(CK)                                                              \
    {                                                                          \
        _Pragma("unroll")                                                      \
        for (int j8 = 0; j8 < 8; ++j8) {                                       \
            const int c_ = (CK) * 32 + sg * 8 + j8;                            \
            sv[j8] = sval ? *(const float4*)(sbase + (size_t)c_ * HW_) : z4;   \
        }                                                                      \
    }
#define SWRITE(DST)                                                            \
    if (sact) {                                                                \
        _Pragma("unroll")                                                      \
        for (int xi = 0; xi < 4; ++xi) {                                       \
            bf16x8 pk;                                                         \
            _Pragma("unroll")                                                  \
            for (int j8 = 0; j8 < 8; ++j8)                                     \
                pk[j8] = (bf16)(((const float*)&sv[j8])[xi] * SC);             \
            *(bf16x8*)((DST) + wb[xi]) = pk;                                   \
        }                                                                      \
    }

    // prologue: stage chunk 0 into buf0 (A loads still in flight above)
    SLOAD(0);
    SWRITE(Bsm);

    bf16x8 afrag[4];
#pragma unroll
    for (int ck = 0; ck < 4; ++ck)
#pragma unroll
        for (int j = 0; j < 8; ++j)
            afrag[ck][j] = (bf16)a_raw[ck * 8 + j];

    f32x4 acc[9][2];
#pragma unroll
    for (int dyi = 0; dyi < 9; ++dyi)
#pragma unroll
        for (int t = 0; t < 2; ++t)
            acc[dyi][t] = (f32x4){0.f, 0.f, 0.f, 0.f};

    __syncthreads();                     // buf0 ready

#pragma unroll
    for (int ck = 0; ck < 4; ++ck) {
        const char* cbuf = Bsm + (ck & 1) * BUFB;
        if (ck < 3) SLOAD(ck + 1);       // issue next chunk's loads BEFORE compute
#pragma unroll
        for (int dyi = 0; dyi < 9; ++dyi) {
            const int rowoff = (w + dyi) * RSTRB;
#pragma unroll
            for (int t = 0; t < 2; ++t) {
                bf16x8 bfrag = *(const bf16x8*)(cbuf + rowoff + rb[t]);
                acc[dyi][t] = __builtin_amdgcn_mfma_f32_16x16x32_bf16(
                    afrag[ck], bfrag, acc[dyi][t], 0, 0, 0);
            }
        }
        if (ck < 3) SWRITE(Bsm + ((ck + 1) & 1) * BUFB);  // write other buffer
        __syncthreads();
    }
#undef SLOAD
#undef SWRITE

    // ---------- epilogue: per-wave LDS transpose -> coalesced stores ----------
    // C/D mapping (verified r6): value acc[dyi][t][rr] = C[m=4g+rr][xl=n+16t];
    // d = xl - m in [0,8] is the dx index; rho = dyi*9 + d.
    float* wsw = (float*)Bsm + w * WSSTR;     // 5248 B/wave, 41984 total < 53248
#pragma unroll
    for (int dyi = 0; dyi < 9; ++dyi)
#pragma unroll
        for (int t = 0; t < 2; ++t)
#pragma unroll
            for (int rr = 0; rr < 4; ++rr) {
                const int m = 4 * g + rr;
                const int d = n + 16 * t - m;
                if ((unsigned)d <= 8u)
                    wsw[(dyi * 9 + d) * 16 + m] = acc[dyi][t][rr];
            }
    __syncthreads();

    const int mm = lane & 15, rg = lane >> 4;
    const size_t ob = (size_t)(b * 81) * HW_ + (size_t)y * W_ + (x0 + mm);
#pragma unroll
    for (int q4 = 0; q4 < 20; ++q4) {
        const int rho = q4 * 4 + rg;
        out[ob + (size_t)rho * HW_] = wsw[rho * 16 + mm];
    }
    if (rg == 0)
        out[ob + (size_t)80 * HW_] = wsw[80 * 16 + mm];
}

extern "C" void kernel_launch(void* const* d_in, const int* in_sizes, int n_in,
                              void* d_out, int out_size, void* d_ws, size_t ws_size,
                              hipStream_t stream) {
    const float* in1 = (const float*)d_in[0];
    const float* in2 = (const float*)d_in[1];
    float* out = (float*)d_out;
    (void)in_sizes; (void)n_in; (void)out_size; (void)d_ws; (void)ws_size;
    hipLaunchKernelGGL(corr_mfma, dim3(NBLK), dim3(NTHR), 0, stream, in1, in2, out);
}